// Round 3
// baseline (241.098 us; speedup 1.0000x reference)
//
#include <hip/hip_runtime.h>

#define MAXN 2048

typedef float f4v __attribute__((ext_vector_type(4)));
typedef int   i4v __attribute__((ext_vector_type(4)));

// Builds the deduplicated selection maps, exactly mirroring _fix_duplicates:
//   sel[j]   = rint(clip(w[j], 0, n-1))                 (round-half-even, like jnp.round)
//   dup[j]   = sel[j] seen at an earlier index
//   empties  = values never selected, consumed in DESCENDING order by dup rank
// block 0 -> column map (n=C), block 1 -> row map (n=R).
// For the row map we additionally emit the INVERSE permutation:
//   invrow[rowmap[i]] = i   (rowmap is a permutation after dedup, so this is exact)
__global__ void build_map_kernel(const float* __restrict__ wc, const float* __restrict__ wr,
                                 int C, int R,
                                 int* __restrict__ colmap, int* __restrict__ rowmap,
                                 int* __restrict__ invrow) {
    const float* w;
    int n;
    int* outmap;
    int* inv;
    if (blockIdx.x == 0) { w = wc; n = C; outmap = colmap; inv = nullptr; }
    else                 { w = wr; n = R; outmap = rowmap; inv = invrow; }

    __shared__ int sel[MAXN];
    __shared__ int first[MAXN];
    __shared__ int emptyslot[MAXN];
    __shared__ int dts[256], ets[256];

    const int t = threadIdx.x;
    const int base = t * 8;           // contiguous 8-element segment per thread
    const float upper = (float)(n - 1);

    for (int k = 0; k < 8; k++) {
        int idx = base + k;
        if (idx < n) {
            float v = w[idx];
            v = fminf(fmaxf(v, 0.0f), upper);
            sel[idx]   = (int)rintf(v);      // RNE == jnp.round
            first[idx] = 0x7fffffff;
        }
    }
    __syncthreads();
    for (int k = 0; k < 8; k++) {
        int idx = base + k;
        if (idx < n) atomicMin(&first[sel[idx]], idx);
    }
    __syncthreads();

    int dflag[8], eflag[8];
    int dsum = 0, esum = 0;
    for (int k = 0; k < 8; k++) {
        int idx = base + k;
        if (idx < n) {
            dflag[k] = (first[sel[idx]] != idx) ? 1 : 0;   // non-first occurrence
            eflag[k] = (first[idx] == 0x7fffffff) ? 1 : 0; // value idx never used
        } else { dflag[k] = 0; eflag[k] = 0; }
        dsum += dflag[k]; esum += eflag[k];
    }

    // block-wide inclusive scans (Hillis-Steele over 256 per-thread sums)
    dts[t] = dsum; ets[t] = esum;
    __syncthreads();
    for (int off = 1; off < 256; off <<= 1) {
        int dv = 0, ev = 0;
        if (t >= off) { dv = dts[t - off]; ev = ets[t - off]; }
        __syncthreads();
        dts[t] += dv; ets[t] += ev;
        __syncthreads();
    }
    const int dexc = dts[t] - dsum;   // dups before my segment
    const int eexc = ets[t] - esum;   // empties (by value) below my segment
    const int E    = ets[255];        // total empties (== total dups)

    // scatter empties: value v with (# empties < v) = p goes to slot E-1-p (descending order)
    int erun = eexc;
    for (int k = 0; k < 8; k++) {
        int idx = base + k;
        if (idx < n && eflag[k]) emptyslot[E - 1 - erun] = idx;
        erun += eflag[k];
    }
    __syncthreads();

    // final map: k-th duplicate (index order) takes emptyslot[k]
    int drun = dexc;
    for (int k = 0; k < 8; k++) {
        int idx = base + k;
        if (idx < n) {
            int val = dflag[k] ? emptyslot[drun] : sel[idx];
            outmap[idx] = val;
            if (inv) inv[val] = idx;   // inverse permutation (no races: val unique)
        }
        drun += dflag[k];
    }
}

// MULTI-ROW PIPELINED SCATTER:
//   out[b, invrow[sr], j] = x[b, sr, colmap[j]]
// Each wave owns 4 CONTIGUOUS source rows. Per row q:
//   1. commit the prefetched row q (registers) into the wave-private LDS slice
//   2. issue global loads for row q+1 into registers (in flight during step 3)
//   3. gather columns from LDS (cmap held in REGISTERS, loaded once per wave)
//      and store the finished row to its permuted destination
// Cross-row pipelining hides HBM load latency under the previous row's
// gather+store work; cmap-in-regs removes 134 MB of repeated map reads.
// No barriers anywhere: a single wave's DS ops execute in order, so the
// write -> gather-read -> next-row-overwrite sequence is safe (proven
// absmax 0.0 in prior rounds).
__global__ __launch_bounds__(256, 4) void scatter_kernel(const float* __restrict__ x,
                              const int* __restrict__ invrow,
                              const int* __restrict__ colmap,
                              float* __restrict__ out,
                              int R, int C, int nrows) {
    __shared__ float lds[4 * MAXN];   // 32 KB: one MAXN-float slice per wave
    const int t    = threadIdx.x;
    const int w    = t >> 6;
    const int lane = t & 63;
    const int wid  = (blockIdx.x << 2) + w;   // global wave id

    float* my  = lds + w * MAXN;
    f4v*   my4 = (f4v*)my;

    // column map in registers: slot k = lane + 64*j
    i4v cm[8];
    const i4v* cmap4 = (const i4v*)colmap;
    #pragma unroll
    for (int j = 0; j < 8; j++) cm[j] = cmap4[lane + (j << 6)];

    const int row0 = wid << 2;                // 4 contiguous source rows
    if (row0 >= nrows) return;

    // prefetch row0 into registers
    f4v pf[8];
    {
        const f4v* src4 = (const f4v*)(x + (size_t)row0 * (size_t)C);
        #pragma unroll
        for (int j = 0; j < 8; j++) pf[j] = src4[lane + (j << 6)];
    }

    for (int q = 0; q < 4; q++) {
        const int s  = row0 + q;
        const int b  = s / R;
        const int sr = s - b * R;
        const int di = invrow[sr];            // destination row within batch
        f4v* dst4 = (f4v*)(out + ((size_t)b * R + di) * (size_t)C);

        // 1. commit prefetched row to LDS
        #pragma unroll
        for (int j = 0; j < 8; j++) my4[lane + (j << 6)] = pf[j];

        // 2. issue next row's loads (overlap with the gather below)
        if (q < 3) {
            const f4v* nsrc = (const f4v*)(x + (size_t)(s + 1) * (size_t)C);
            #pragma unroll
            for (int j = 0; j < 8; j++) pf[j] = nsrc[lane + (j << 6)];
        }

        // 3. column gather + coalesced store of the whole row
        #pragma unroll
        for (int j = 0; j < 8; j++) {
            i4v c = cm[j];
            f4v v;
            v.x = my[c.x];
            v.y = my[c.y];
            v.z = my[c.z];
            v.w = my[c.w];
            dst4[lane + (j << 6)] = v;
        }
    }
}

extern "C" void kernel_launch(void* const* d_in, const int* in_sizes, int n_in,
                              void* d_out, int out_size, void* d_ws, size_t ws_size,
                              hipStream_t stream) {
    const float* x  = (const float*)d_in[0];
    const float* wc = (const float*)d_in[1];
    const float* wr = (const float*)d_in[2];
    const int C = in_sizes[1];            // 2048
    const int R = in_sizes[2];            // 1024
    const int B = in_sizes[0] / (R * C);  // 16

    int* colmap = (int*)d_ws;
    int* rowmap = colmap + C;
    int* invrow = rowmap + R;

    build_map_kernel<<<2, 256, 0, stream>>>(wc, wr, C, R, colmap, rowmap, invrow);

    const int nrows = B * R;              // 16384 source rows, 4 per wave
    const int nblocks = (nrows + 15) / 16;
    scatter_kernel<<<nblocks, 256, 0, stream>>>(x, invrow, colmap,
                                                (float*)d_out, R, C, nrows);
}